// Round 8
// baseline (189.749 us; speedup 1.0000x reference)
//
#include <hip/hip_runtime.h>
#include <hip/hip_bf16.h>

// MessagePassing: out[dst[e], :] += x[src[e], :]
// x: [N=50000, D=64] fp32; edge_index: [2, E=800000] int32 (src row, dst row)
// Round 7: same theory as round 6 (scatter is write-back-amplification bound;
// keep perm lines in L2 by streaming edge reads non-temporally), with the
// compile fix: __builtin_nontemporal_load needs a native vector type, not
// HIP_vector_type. Use ext_vector_type(4) int.

#define N_NODES_C 50000
#define D_FEAT_C 64
#define SCAN_B 256
#define NB_SCAN ((N_NODES_C + SCAN_B - 1) / SCAN_B)   // 196

static_assert(N_NODES_C < 65536, "perm uses uint16 src indices");

typedef int v4i __attribute__((ext_vector_type(4)));

__global__ void k_hist(const int* __restrict__ dst, int* __restrict__ deg, int E) {
    int i = blockIdx.x * blockDim.x + threadIdx.x;
    int stride = gridDim.x * blockDim.x;
    int n4 = E >> 2;
    const v4i* d4 = (const v4i*)dst;
    for (int j = i; j < n4; j += stride) {
        v4i v = __builtin_nontemporal_load(&d4[j]);
        atomicAdd(&deg[v.x], 1);
        atomicAdd(&deg[v.y], 1);
        atomicAdd(&deg[v.z], 1);
        atomicAdd(&deg[v.w], 1);
    }
    for (int j = (n4 << 2) + i; j < E; j += stride) atomicAdd(&deg[dst[j]], 1);
}

// Per-block reduction of 256 deg entries -> bsum[block]
__global__ void k_part(const int* __restrict__ deg, int* __restrict__ bsum, int N) {
    __shared__ int s[SCAN_B];
    int t = threadIdx.x;
    int i = blockIdx.x * SCAN_B + t;
    s[t] = (i < N) ? deg[i] : 0;
    __syncthreads();
    for (int off = SCAN_B / 2; off > 0; off >>= 1) {
        if (t < off) s[t] += s[t + off];
        __syncthreads();
    }
    if (t == 0) bsum[blockIdx.x] = s[0];
}

// Single small block: exclusive scan of nb (<=256) block sums; writes offs[N].
__global__ void k_scanb(const int* __restrict__ bsum, int* __restrict__ bpre,
                        int* __restrict__ offs, int nb, int N) {
    __shared__ int s[SCAN_B];
    int t = threadIdx.x;
    int v = (t < nb) ? bsum[t] : 0;
    s[t] = v;
    __syncthreads();
    for (int off = 1; off < SCAN_B; off <<= 1) {
        int u = (t >= off) ? s[t - off] : 0;
        __syncthreads();
        s[t] += u;
        __syncthreads();
    }
    if (t < nb) bpre[t] = s[t] - v;       // exclusive prefix of block sums
    if (t == SCAN_B - 1) offs[N] = s[SCAN_B - 1];  // grand total
}

// Intra-block exclusive scan + block prefix -> offs/cursor
__global__ void k_offs(const int* __restrict__ deg, const int* __restrict__ bpre,
                       int* __restrict__ offs, int* __restrict__ cursor, int N) {
    __shared__ int s[SCAN_B];
    int t = threadIdx.x;
    int i = blockIdx.x * SCAN_B + t;
    int v = (i < N) ? deg[i] : 0;
    s[t] = v;
    __syncthreads();
    for (int off = 1; off < SCAN_B; off <<= 1) {
        int u = (t >= off) ? s[t - off] : 0;
        __syncthreads();
        s[t] += u;
        __syncthreads();
    }
    if (i < N) {
        int o = bpre[blockIdx.x] + s[t] - v;
        offs[i] = o;
        cursor[i] = o;
    }
}

__global__ void k_scatter(const int* __restrict__ src, const int* __restrict__ dst,
                          int* __restrict__ cursor, unsigned short* __restrict__ perm,
                          int E) {
    int i = blockIdx.x * blockDim.x + threadIdx.x;
    int stride = gridDim.x * blockDim.x;
    int n4 = E >> 2;
    const v4i* s4 = (const v4i*)src;
    const v4i* d4 = (const v4i*)dst;
    for (int j = i; j < n4; j += stride) {
        v4i s = __builtin_nontemporal_load(&s4[j]);
        v4i d = __builtin_nontemporal_load(&d4[j]);
        perm[atomicAdd(&cursor[d.x], 1)] = (unsigned short)s.x;
        perm[atomicAdd(&cursor[d.y], 1)] = (unsigned short)s.y;
        perm[atomicAdd(&cursor[d.z], 1)] = (unsigned short)s.z;
        perm[atomicAdd(&cursor[d.w], 1)] = (unsigned short)s.w;
    }
    for (int j = (n4 << 2) + i; j < E; j += stride) {
        perm[atomicAdd(&cursor[dst[j]], 1)] = (unsigned short)src[j];
    }
}

// 64 lanes per node: lane t accumulates feature t across the node's edges.
__global__ void k_gather(const float* __restrict__ x,
                         const unsigned short* __restrict__ perm,
                         const int* __restrict__ offs, float* __restrict__ out) {
    int node = blockIdx.x * (blockDim.x >> 6) + (threadIdx.x >> 6);
    int lane = threadIdx.x & 63;
    if (node >= N_NODES_C) return;

    int b = offs[node];
    int e = offs[node + 1];
    float a0 = 0.f, a1 = 0.f, a2 = 0.f, a3 = 0.f;
    int i = b;
    for (; i + 3 < e; i += 4) {
        int s0 = __builtin_nontemporal_load(&perm[i]);
        int s1 = __builtin_nontemporal_load(&perm[i + 1]);
        int s2 = __builtin_nontemporal_load(&perm[i + 2]);
        int s3 = __builtin_nontemporal_load(&perm[i + 3]);
        a0 += x[(size_t)s0 * D_FEAT_C + lane];
        a1 += x[(size_t)s1 * D_FEAT_C + lane];
        a2 += x[(size_t)s2 * D_FEAT_C + lane];
        a3 += x[(size_t)s3 * D_FEAT_C + lane];
    }
    for (; i < e; ++i) a0 += x[(size_t)perm[i] * D_FEAT_C + lane];
    out[(size_t)node * D_FEAT_C + lane] = (a0 + a1) + (a2 + a3);
}

extern "C" void kernel_launch(void* const* d_in, const int* in_sizes, int n_in,
                              void* d_out, int out_size, void* d_ws, size_t ws_size,
                              hipStream_t stream) {
    const float* x = (const float*)d_in[0];
    const int* edge_index = (const int*)d_in[1];
    float* out = (float*)d_out;

    const int E = in_sizes[1] / 2;            // [2, E] flattened row-major
    const int* src = edge_index;              // edge_index[0]
    const int* dst = edge_index + E;          // edge_index[1]

    // Workspace (ints): deg[N] | offs[N+1] | cursor[N] | bsum[NB] | bpre[NB] | perm16[E]
    int* deg    = (int*)d_ws;
    int* offs   = deg + N_NODES_C;
    int* cursor = offs + N_NODES_C + 1;
    int* bsum   = cursor + N_NODES_C;
    int* bpre   = bsum + NB_SCAN;
    unsigned short* perm = (unsigned short*)(bpre + NB_SCAN);

    (void)hipMemsetAsync(deg, 0, (size_t)N_NODES_C * sizeof(int), stream);

    const int block = 256;
    const int gridE4 = ((E / 4) + block - 1) / block;  // 1 edge-quad per thread
    k_hist<<<gridE4, block, 0, stream>>>(dst, deg, E);
    k_part<<<NB_SCAN, SCAN_B, 0, stream>>>(deg, bsum, N_NODES_C);
    k_scanb<<<1, SCAN_B, 0, stream>>>(bsum, bpre, offs, NB_SCAN, N_NODES_C);
    k_offs<<<NB_SCAN, SCAN_B, 0, stream>>>(deg, bpre, offs, cursor, N_NODES_C);
    k_scatter<<<gridE4, block, 0, stream>>>(src, dst, cursor, perm, E);

    const int nodes_per_block = block / 64;   // 4
    const int gridN = (N_NODES_C + nodes_per_block - 1) / nodes_per_block;
    k_gather<<<gridN, block, 0, stream>>>(x, perm, offs, out);
}

// Round 9
// 188.211 us; speedup vs baseline: 1.0082x; 1.0082x over previous
//
#include <hip/hip_runtime.h>
#include <hip/hip_bf16.h>

// MessagePassing: out[dst[e], :] += x[src[e], :]
// x: [N=50000, D=64] fp32; edge_index: [2, E=800000] int32 (src row, dst row)
// Round 8: NT loads refuted (WRITE_SIZE unchanged 41MB). New theory: perm
// write amplification is CROSS-XCD — each 64B perm line is dirtied by blocks
// on all 8 XCDs; non-coherent L2s can't merge, so each XCD issues its own
// partial-line writeback. Fix: XCD-binned scatter. Node space is split into
// 8 ranges; block b only scatters edges with dst in range (b&7), which under
// round-robin dispatch = its own XCD. All writes to a perm line then come
// from one XCD (merge in its L2; footprint 200KB/XCD). dst stream read 8x
// but LLC-resident. Binning is a locality heuristic only - correctness never
// depends on the block->XCD mapping.

#define N_NODES_C 50000
#define D_FEAT_C 64
#define SCAN_B 256
#define NB_SCAN ((N_NODES_C + SCAN_B - 1) / SCAN_B)   // 196
#define NXCD 8
#define NODES_PER_RANGE ((N_NODES_C + NXCD - 1) / NXCD)  // 6250

static_assert(N_NODES_C < 65536, "perm uses uint16 src indices");

typedef int v4i __attribute__((ext_vector_type(4)));

__global__ void k_hist(const int* __restrict__ dst, int* __restrict__ deg, int E) {
    int i = blockIdx.x * blockDim.x + threadIdx.x;
    int stride = gridDim.x * blockDim.x;
    int n4 = E >> 2;
    const v4i* d4 = (const v4i*)dst;
    for (int j = i; j < n4; j += stride) {
        v4i v = __builtin_nontemporal_load(&d4[j]);
        atomicAdd(&deg[v.x], 1);
        atomicAdd(&deg[v.y], 1);
        atomicAdd(&deg[v.z], 1);
        atomicAdd(&deg[v.w], 1);
    }
    for (int j = (n4 << 2) + i; j < E; j += stride) atomicAdd(&deg[dst[j]], 1);
}

// Per-block reduction of 256 deg entries -> bsum[block]
__global__ void k_part(const int* __restrict__ deg, int* __restrict__ bsum, int N) {
    __shared__ int s[SCAN_B];
    int t = threadIdx.x;
    int i = blockIdx.x * SCAN_B + t;
    s[t] = (i < N) ? deg[i] : 0;
    __syncthreads();
    for (int off = SCAN_B / 2; off > 0; off >>= 1) {
        if (t < off) s[t] += s[t + off];
        __syncthreads();
    }
    if (t == 0) bsum[blockIdx.x] = s[0];
}

// Single small block: exclusive scan of nb (<=256) block sums; writes offs[N].
__global__ void k_scanb(const int* __restrict__ bsum, int* __restrict__ bpre,
                        int* __restrict__ offs, int nb, int N) {
    __shared__ int s[SCAN_B];
    int t = threadIdx.x;
    int v = (t < nb) ? bsum[t] : 0;
    s[t] = v;
    __syncthreads();
    for (int off = 1; off < SCAN_B; off <<= 1) {
        int u = (t >= off) ? s[t - off] : 0;
        __syncthreads();
        s[t] += u;
        __syncthreads();
    }
    if (t < nb) bpre[t] = s[t] - v;       // exclusive prefix of block sums
    if (t == SCAN_B - 1) offs[N] = s[SCAN_B - 1];  // grand total
}

// Intra-block exclusive scan + block prefix -> offs/cursor
__global__ void k_offs(const int* __restrict__ deg, const int* __restrict__ bpre,
                       int* __restrict__ offs, int* __restrict__ cursor, int N) {
    __shared__ int s[SCAN_B];
    int t = threadIdx.x;
    int i = blockIdx.x * SCAN_B + t;
    int v = (i < N) ? deg[i] : 0;
    s[t] = v;
    __syncthreads();
    for (int off = 1; off < SCAN_B; off <<= 1) {
        int u = (t >= off) ? s[t - off] : 0;
        __syncthreads();
        s[t] += u;
        __syncthreads();
    }
    if (i < N) {
        int o = bpre[blockIdx.x] + s[t] - v;
        offs[i] = o;
        cursor[i] = o;
    }
}

// XCD-binned scatter: block b handles only dst in [lo,hi) for range (b&7).
// Blocks with the same (b&7) land on the same XCD under round-robin dispatch,
// so each perm cache line is written by exactly one XCD -> L2 merges.
__global__ void k_scatter(const int* __restrict__ src, const int* __restrict__ dst,
                          int* __restrict__ cursor, unsigned short* __restrict__ perm,
                          int E) {
    int range = blockIdx.x & (NXCD - 1);
    int sub   = blockIdx.x >> 3;           // index within this range's group
    int nsub  = gridDim.x >> 3;            // blocks per range
    int lo = range * NODES_PER_RANGE;
    int hi = lo + NODES_PER_RANGE;         // may exceed N; dst < N anyway

    int n4 = E >> 2;
    const v4i* s4 = (const v4i*)src;
    const v4i* d4 = (const v4i*)dst;
    int start = sub * blockDim.x + threadIdx.x;
    int stride = nsub * blockDim.x;

    for (int j = start; j < n4; j += stride) {
        v4i d = d4[j];                     // plain load: we WANT L2/LLC reuse
        bool m0 = (d.x >= lo) & (d.x < hi);
        bool m1 = (d.y >= lo) & (d.y < hi);
        bool m2 = (d.z >= lo) & (d.z < hi);
        bool m3 = (d.w >= lo) & (d.w < hi);
        if (m0 | m1 | m2 | m3) {
            v4i s = s4[j];
            if (m0) perm[atomicAdd(&cursor[d.x], 1)] = (unsigned short)s.x;
            if (m1) perm[atomicAdd(&cursor[d.y], 1)] = (unsigned short)s.y;
            if (m2) perm[atomicAdd(&cursor[d.z], 1)] = (unsigned short)s.z;
            if (m3) perm[atomicAdd(&cursor[d.w], 1)] = (unsigned short)s.w;
        }
    }
    for (int j = (n4 << 2) + start; j < E; j += stride) {
        int d = dst[j];
        if (d >= lo && d < hi)
            perm[atomicAdd(&cursor[d], 1)] = (unsigned short)src[j];
    }
}

// 64 lanes per node: lane t accumulates feature t across the node's edges.
__global__ void k_gather(const float* __restrict__ x,
                         const unsigned short* __restrict__ perm,
                         const int* __restrict__ offs, float* __restrict__ out) {
    int node = blockIdx.x * (blockDim.x >> 6) + (threadIdx.x >> 6);
    int lane = threadIdx.x & 63;
    if (node >= N_NODES_C) return;

    int b = offs[node];
    int e = offs[node + 1];
    float a0 = 0.f, a1 = 0.f, a2 = 0.f, a3 = 0.f;
    int i = b;
    for (; i + 3 < e; i += 4) {
        int s0 = __builtin_nontemporal_load(&perm[i]);
        int s1 = __builtin_nontemporal_load(&perm[i + 1]);
        int s2 = __builtin_nontemporal_load(&perm[i + 2]);
        int s3 = __builtin_nontemporal_load(&perm[i + 3]);
        a0 += x[(size_t)s0 * D_FEAT_C + lane];
        a1 += x[(size_t)s1 * D_FEAT_C + lane];
        a2 += x[(size_t)s2 * D_FEAT_C + lane];
        a3 += x[(size_t)s3 * D_FEAT_C + lane];
    }
    for (; i < e; ++i) a0 += x[(size_t)perm[i] * D_FEAT_C + lane];
    out[(size_t)node * D_FEAT_C + lane] = (a0 + a1) + (a2 + a3);
}

extern "C" void kernel_launch(void* const* d_in, const int* in_sizes, int n_in,
                              void* d_out, int out_size, void* d_ws, size_t ws_size,
                              hipStream_t stream) {
    const float* x = (const float*)d_in[0];
    const int* edge_index = (const int*)d_in[1];
    float* out = (float*)d_out;

    const int E = in_sizes[1] / 2;            // [2, E] flattened row-major
    const int* src = edge_index;              // edge_index[0]
    const int* dst = edge_index + E;          // edge_index[1]

    // Workspace (ints): deg[N] | offs[N+1] | cursor[N] | bsum[NB] | bpre[NB] | perm16[E]
    int* deg    = (int*)d_ws;
    int* offs   = deg + N_NODES_C;
    int* cursor = offs + N_NODES_C + 1;
    int* bsum   = cursor + N_NODES_C;
    int* bpre   = bsum + NB_SCAN;
    unsigned short* perm = (unsigned short*)(bpre + NB_SCAN);

    (void)hipMemsetAsync(deg, 0, (size_t)N_NODES_C * sizeof(int), stream);

    const int block = 256;
    const int gridE4 = ((E / 4) + block - 1) / block;  // 1 edge-quad per thread
    k_hist<<<gridE4, block, 0, stream>>>(dst, deg, E);
    k_part<<<NB_SCAN, SCAN_B, 0, stream>>>(deg, bsum, N_NODES_C);
    k_scanb<<<1, SCAN_B, 0, stream>>>(bsum, bpre, offs, NB_SCAN, N_NODES_C);
    k_offs<<<NB_SCAN, SCAN_B, 0, stream>>>(deg, bpre, offs, cursor, N_NODES_C);
    // 1024 blocks = 128 per node-range; range = blockIdx & 7 matches the
    // default round-robin block->XCD assignment.
    k_scatter<<<1024, block, 0, stream>>>(src, dst, cursor, perm, E);

    const int nodes_per_block = block / 64;   // 4
    const int gridN = (N_NODES_C + nodes_per_block - 1) / nodes_per_block;
    k_gather<<<gridN, block, 0, stream>>>(x, perm, offs, out);
}